// Round 13
// baseline (764.796 us; speedup 1.0000x reference)
//
#include <hip/hip_runtime.h>
#include <math.h>

#define N_NODES 50000
#define N_EDGES 800000
#define DCH 128
#define N_LAYERS 9
#define N_GRAPHS 256
#define EPSF 1e-5f
#define NCHUNK 196   // ceil(50000/256)
#define SL_SZ 6250   // N_NODES / 8 slices

typedef __attribute__((ext_vector_type(8))) short short8;   // 8 bf16 = 4 VGPRs
typedef __attribute__((ext_vector_type(4))) float floatx4;

static __device__ __forceinline__ unsigned short f2bf(float f) {
    unsigned int u = __float_as_uint(f);
    unsigned int r = (u + 0x7fffu + ((u >> 16) & 1u)) >> 16;  // RNE
    return (unsigned short)r;
}
static __device__ __forceinline__ unsigned int pack_bf2(float a, float b) {
    return (unsigned int)f2bf(a) | ((unsigned int)f2bf(b) << 16);
}
static __device__ __forceinline__ float bflo(unsigned int u) { return __uint_as_float(u << 16); }
static __device__ __forceinline__ float bfhi(unsigned int u) { return __uint_as_float(u & 0xffff0000u); }

// descending-degree bucket (heavy nodes get low p -> dispatched first, LPT)
static __device__ __forceinline__ int dbucket(int d) { return 63 - min(d, 63); }

// ---------------- degree histogram (original node space) ----------------
__global__ void hist_kernel(const int* __restrict__ dst, int* __restrict__ deg) {
    int t = blockIdx.x * 256 + threadIdx.x;   // grid covers exactly N_EDGES
    atomicAdd(&deg[dst[t]], 1);
}

// ---------------- descending counting sort, two-level (no global hotspots) ----------------
__global__ __launch_bounds__(256) void dsort_hist_kernel(const int* __restrict__ deg,
                                                         int* __restrict__ bhist) {
    __shared__ int lh[64];
    int t = threadIdx.x;
    if (t < 64) lh[t] = 0;
    __syncthreads();
    int n = blockIdx.x * 256 + t;
    if (n < N_NODES) atomicAdd(&lh[dbucket(deg[n])], 1);
    __syncthreads();
    if (t < 64) bhist[blockIdx.x * 64 + t] = lh[t];
}

__global__ __launch_bounds__(64) void dsort_scan_kernel(const int* __restrict__ bhist,
                                                        int* __restrict__ boff) {
    __shared__ int tot[64];
    __shared__ int base[64];
    int b = threadIdx.x;  // thread b owns bucket b
    int s = 0;
    for (int blk = 0; blk < NCHUNK; blk++) s += bhist[blk * 64 + b];
    tot[b] = s;
    __syncthreads();
    if (b == 0) {
        int run = 0;
        for (int i = 0; i < 64; i++) { base[i] = run; run += tot[i]; }
    }
    __syncthreads();
    int run = base[b];
    for (int blk = 0; blk < NCHUNK; blk++) {
        boff[blk * 64 + b] = run;
        run += bhist[blk * 64 + b];
    }
}

__global__ __launch_bounds__(256) void dsort_scatter_kernel(const int* __restrict__ deg,
                                                            const int* __restrict__ boff,
                                                            int* __restrict__ nperm,
                                                            int* __restrict__ inv) {
    __shared__ int cur[64];
    int t = threadIdx.x;
    if (t < 64) cur[t] = boff[blockIdx.x * 64 + t];
    __syncthreads();
    int n = blockIdx.x * 256 + t;
    if (n < N_NODES) {
        int p = atomicAdd(&cur[dbucket(deg[n])], 1);  // LDS atomic, intra-block only
        nperm[p] = n;
        inv[n] = p;
    }
}

// dstinv[e] = inv[dst[e]] (one pass; avoids 8x random inv gathers in scatter)
__global__ void dstinv_kernel(const int* __restrict__ dst, const int* __restrict__ inv,
                              int* __restrict__ dstinv) {
    int t = blockIdx.x * 256 + threadIdx.x;
    dstinv[t] = inv[dst[t]];
}

// ---------------- CSR build in p-space ----------------
__global__ __launch_bounds__(256) void chunksum_kernel(const int* __restrict__ deg,
                                                       const int* __restrict__ nperm,
                                                       int* __restrict__ csum) {
    int t = threadIdx.x;
    int i = blockIdx.x * 256 + t;
    int v = (i < N_NODES) ? deg[nperm[i]] : 0;
    __shared__ int sh[4];
    for (int off = 32; off >= 1; off >>= 1) v += __shfl_down(v, off);
    if ((t & 63) == 0) sh[t >> 6] = v;
    __syncthreads();
    if (t == 0) csum[blockIdx.x] = sh[0] + sh[1] + sh[2] + sh[3];
}

__global__ __launch_bounds__(256) void chunkscan_kernel(const int* __restrict__ csum,
                                                        int* __restrict__ coff) {
    __shared__ int sh[256];
    int t = threadIdx.x;
    sh[t] = (t < NCHUNK) ? csum[t] : 0;
    __syncthreads();
    for (int off = 1; off < 256; off <<= 1) {
        int v = (t >= off) ? sh[t - off] : 0;
        __syncthreads();
        sh[t] += v;
        __syncthreads();
    }
    if (t < NCHUNK) coff[t] = t ? sh[t - 1] : 0;  // exclusive
}

__global__ __launch_bounds__(256) void applyscan_kernel(const int* __restrict__ deg,
                                                        const int* __restrict__ nperm,
                                                        const int* __restrict__ coff,
                                                        int* __restrict__ rowp,
                                                        int* __restrict__ cursor) {
    __shared__ int sh[256];
    int t = threadIdx.x;
    int i = blockIdx.x * 256 + t;
    int d = (i < N_NODES) ? deg[nperm[i]] : 0;
    sh[t] = d;
    __syncthreads();
    for (int off = 1; off < 256; off <<= 1) {
        int v = (t >= off) ? sh[t - off] : 0;
        __syncthreads();
        sh[t] += v;
        __syncthreads();
    }
    int excl = coff[blockIdx.x] + (t ? sh[t - 1] : 0);
    if (i < N_NODES) {
        rowp[i] = excl;
        cursor[i] = excl;
    }
    if (i == N_NODES - 1) rowp[N_NODES] = N_EDGES;
}

// XCD-sliced scatter in p-space: block (chunk, s=blockIdx&7) keeps edges whose
// p-space dst is in slice s -> contiguous erec region stays in that XCD's L2.
__global__ __launch_bounds__(256) void scatter_kernel(const int* __restrict__ src,
                                                      const int* __restrict__ dstinv,
                                                      const int* __restrict__ inv,
                                                      const float* __restrict__ eattr,
                                                      int* __restrict__ cursor,
                                                      uint4* __restrict__ erec) {
    int s = blockIdx.x & 7;
    int chunk = blockIdx.x >> 3;
    int e0 = chunk * 1024 + threadIdx.x * 4;
    if (e0 >= N_EDGES) return;
    int4 d4 = *(const int4*)(dstinv + e0);
#pragma unroll
    for (int k = 0; k < 4; k++) {
        int e = e0 + k;
        int d = (k == 0) ? d4.x : (k == 1) ? d4.y : (k == 2) ? d4.z : d4.w;
        if (d / SL_SZ == s) {
            int p = atomicAdd(&cursor[d], 1);
            float4 a = ((const float4*)eattr)[e];
            erec[p] = make_uint4((unsigned int)inv[src[e]],
                                 pack_bf2(a.x, a.y), pack_bf2(a.z, a.w), 0u);
        }
    }
}

// ---------------- per-node src-sort of edge records (gather locality) ----------------
// One wave per node; in-register 64-element bitonic sort by src key. All waves
// then walk their lists in ascending src order -> concurrent gathers cluster in
// the same src quantile window (~L2-resident). deg>64 nodes (prob ~0) skipped.
__global__ __launch_bounds__(256) void sortrec_kernel(const int* __restrict__ rowp,
                                                      uint4* __restrict__ erec) {
    int n = blockIdx.x * 4 + (threadIdx.x >> 6);
    int l = threadIdx.x & 63;
    int start = rowp[n], end = rowp[n + 1];
    int d = end - start;
    if (d <= 1 || d > 64) return;
    uint4 r = (l < d) ? erec[start + l] : make_uint4(0xFFFFFFFFu, 0u, 0u, 0u);
#pragma unroll
    for (int k = 2; k <= 64; k <<= 1) {
        for (int j = k >> 1; j > 0; j >>= 1) {
            uint4 o;
            o.x = (unsigned int)__shfl_xor((int)r.x, j);
            o.y = (unsigned int)__shfl_xor((int)r.y, j);
            o.z = (unsigned int)__shfl_xor((int)r.z, j);
            o.w = (unsigned int)__shfl_xor((int)r.w, j);
            bool up = ((l & k) == 0);
            bool lower = ((l & j) == 0);
            bool takeMin = (up == lower);
            if (takeMin) { if (o.x < r.x) r = o; }
            else         { if (o.x > r.x) r = o; }
        }
    }
    if (l < d) erec[start + l] = r;
}

// ---------------- conv weights -> MFMA B-fragment layout, bf16 ----------------
__global__ __launch_bounds__(256) void wconv_kernel(const float* __restrict__ convW,
                                                    uint4* __restrict__ wb) {
    int tid = blockIdx.x * 256 + threadIdx.x;  // 72 blocks * 256 = 18432 exactly
    int lane = tid & 63;
    int t = (tid >> 6) & 31;
    int layer = tid >> 11;
    int jt = t >> 2, kt = t & 3;
    int quad = lane >> 4, col = lane & 15;
    const float* Wl = convW + (size_t)layer * DCH * DCH;
    int kbase = kt * 32 + quad * 8;
    int ch = jt * 16 + col;
    unsigned int d0 = pack_bf2(Wl[(kbase + 0) * DCH + ch], Wl[(kbase + 1) * DCH + ch]);
    unsigned int d1 = pack_bf2(Wl[(kbase + 2) * DCH + ch], Wl[(kbase + 3) * DCH + ch]);
    unsigned int d2 = pack_bf2(Wl[(kbase + 4) * DCH + ch], Wl[(kbase + 5) * DCH + ch]);
    unsigned int d3 = pack_bf2(Wl[(kbase + 6) * DCH + ch], Wl[(kbase + 7) * DCH + ch]);
    wb[tid] = make_uint4(d0, d1, d2, d3);
}

// ---------------- h0 = x @ Wv, written to p-space rows ----------------
__global__ void h0_kernel(const float* __restrict__ x, const float* __restrict__ Wv,
                          const int* __restrict__ inv,
                          float* __restrict__ h, unsigned int* __restrict__ hbf) {
    int t = blockIdx.x * 256 + threadIdx.x;
    int n = t >> 6, l = t & 63;
    const float* xr = x + n * 13;
    float s0 = 0.f, s1 = 0.f;
#pragma unroll
    for (int j = 0; j < 13; j++) {
        float xv = xr[j];
        s0 = fmaf(xv, Wv[j * 128 + 2 * l], s0);
        s1 = fmaf(xv, Wv[j * 128 + 2 * l + 1], s1);
    }
    int p = inv[n];  // wave-uniform
    ((float2*)h)[(size_t)p * 64 + l] = make_float2(s0, s1);
    hbf[(size_t)p * 64 + l] = pack_bf2(s0, s1);
}

// ---------------- fused layer (p-space): aggregation + MFMA GEMM + epilogue ----------------
#define VSTRIDE 68  // node row stride in uints (64 + 4 pad)
#define OLP 132     // epilogue row: 128 + 4
__global__ __launch_bounds__(256) void layer_kernel(const float* __restrict__ hin,
                                                    const unsigned int* __restrict__ hbfA,
                                                    const uint4* __restrict__ erec,
                                                    const int* __restrict__ rowp,
                                                    const float* __restrict__ We,
                                                    const short8* __restrict__ wbL,
                                                    const float* __restrict__ b,
                                                    float* __restrict__ hout,
                                                    unsigned int* __restrict__ hbfB,
                                                    int write_hbf) {
    __shared__ unsigned int vsh[16 * VSTRIDE];  // 4.25 KiB
    __shared__ float ol[16 * OLP];              // 8.25 KiB
    int tid = threadIdx.x;
    int lane = tid & 63;
    int wave = tid >> 6;
    int nb = blockIdx.x * 16;  // 3125 blocks * 16 = 50000 exactly
    float w00 = We[0 * 128 + 2 * lane], w01 = We[0 * 128 + 2 * lane + 1];
    float w10 = We[1 * 128 + 2 * lane], w11 = We[1 * 128 + 2 * lane + 1];
    float w20 = We[2 * 128 + 2 * lane], w21 = We[2 * 128 + 2 * lane + 1];
    float w30 = We[3 * 128 + 2 * lane], w31 = We[3 * 128 + 2 * lane + 1];
    const float2* h2 = (const float2*)hin;
    // ---- aggregation: 4 nodes per wave, sequential ----
    for (int j = 0; j < 4; j++) {
        int nl = wave * 4 + j;
        int n = nb + nl;
        int start = rowp[n], end = rowp[n + 1];
        float a0 = 0.f, a1 = 0.f;
        int e = start;
        for (; e + 4 <= end; e += 4) {
            uint4 r0 = erec[e], r1 = erec[e + 1], r2 = erec[e + 2], r3 = erec[e + 3];
            unsigned int u0 = hbfA[(size_t)r0.x * 64 + lane];
            unsigned int u1 = hbfA[(size_t)r1.x * 64 + lane];
            unsigned int u2 = hbfA[(size_t)r2.x * 64 + lane];
            unsigned int u3 = hbfA[(size_t)r3.x * 64 + lane];
            float p0 = fmaf(bflo(r0.y), w00, fmaf(bfhi(r0.y), w10, fmaf(bflo(r0.z), w20, bfhi(r0.z) * w30)));
            float p1 = fmaf(bflo(r0.y), w01, fmaf(bfhi(r0.y), w11, fmaf(bflo(r0.z), w21, bfhi(r0.z) * w31)));
            float q0 = fmaf(bflo(r1.y), w00, fmaf(bfhi(r1.y), w10, fmaf(bflo(r1.z), w20, bfhi(r1.z) * w30)));
            float q1 = fmaf(bflo(r1.y), w01, fmaf(bfhi(r1.y), w11, fmaf(bflo(r1.z), w21, bfhi(r1.z) * w31)));
            float s0 = fmaf(bflo(r2.y), w00, fmaf(bfhi(r2.y), w10, fmaf(bflo(r2.z), w20, bfhi(r2.z) * w30)));
            float s1 = fmaf(bflo(r2.y), w01, fmaf(bfhi(r2.y), w11, fmaf(bflo(r2.z), w21, bfhi(r2.z) * w31)));
            float t0 = fmaf(bflo(r3.y), w00, fmaf(bfhi(r3.y), w10, fmaf(bflo(r3.z), w20, bfhi(r3.z) * w30)));
            float t1 = fmaf(bflo(r3.y), w01, fmaf(bfhi(r3.y), w11, fmaf(bflo(r3.z), w21, bfhi(r3.z) * w31)));
            a0 += fmaxf(bflo(u0) + p0, 0.f);
            a1 += fmaxf(bfhi(u0) + p1, 0.f);
            a0 += fmaxf(bflo(u1) + q0, 0.f);
            a1 += fmaxf(bfhi(u1) + q1, 0.f);
            a0 += fmaxf(bflo(u2) + s0, 0.f);
            a1 += fmaxf(bfhi(u2) + s1, 0.f);
            a0 += fmaxf(bflo(u3) + t0, 0.f);
            a1 += fmaxf(bfhi(u3) + t1, 0.f);
        }
        for (; e < end; e++) {
            uint4 r0 = erec[e];
            unsigned int u0 = hbfA[(size_t)r0.x * 64 + lane];
            float p0 = fmaf(bflo(r0.y), w00, fmaf(bfhi(r0.y), w10, fmaf(bflo(r0.z), w20, bfhi(r0.z) * w30)));
            float p1 = fmaf(bflo(r0.y), w01, fmaf(bfhi(r0.y), w11, fmaf(bflo(r0.z), w21, bfhi(r0.z) * w31)));
            a0 += fmaxf(bflo(u0) + p0, 0.f);
            a1 += fmaxf(bfhi(u0) + p1, 0.f);
        }
        float2 hn = h2[(size_t)n * 64 + lane];
        float vx = fmaf(hn.x, 1.f + EPSF, a0);
        float vy = fmaf(hn.y, 1.f + EPSF, a1);
        vsh[nl * VSTRIDE + lane] = pack_bf2(vx, vy);
    }
    __syncthreads();
    // ---- MFMA: shared 16-node A, each wave does jt = 2*wave, 2*wave+1 ----
    int col = lane & 15, quad = lane >> 4;
    short8 a[4];
#pragma unroll
    for (int kt = 0; kt < 4; kt++) {
        a[kt] = *(const short8*)(vsh + col * VSTRIDE + kt * 16 + quad * 4);
    }
#pragma unroll
    for (int jj = 0; jj < 2; jj++) {
        int jt = wave * 2 + jj;
        floatx4 acc = {0.f, 0.f, 0.f, 0.f};
#pragma unroll
        for (int kt = 0; kt < 4; kt++) {
            short8 bf = wbL[(jt * 4 + kt) * 64 + lane];
            acc = __builtin_amdgcn_mfma_f32_16x16x32_bf16(a[kt], bf, acc, 0, 0, 0);
        }
        float bv = b[jt * 16 + col];
#pragma unroll
        for (int r = 0; r < 4; r++) {
            ol[(quad * 4 + r) * OLP + jt * 16 + col] = fmaxf(acc[r] + bv, 0.f);
        }
    }
    __syncthreads();
    // ---- coalesced epilogue: 16 nodes x 32 float4-chunks = 512 items ----
    const float4* h4 = (const float4*)hin;
    float4* o4 = (float4*)hout;
    uint2* b2 = (uint2*)hbfB;
#pragma unroll
    for (int i = 0; i < 2; i++) {
        int idx = i * 256 + tid;            // 0..511
        int nl = idx >> 5, c4 = idx & 31;
        int node = nb + nl;
        const float* row = ol + nl * OLP + c4 * 4;
        float4 hh = h4[(size_t)node * 32 + c4];
        float4 r;
        r.x = row[0] + hh.x;
        r.y = row[1] + hh.y;
        r.z = row[2] + hh.z;
        r.w = row[3] + hh.w;
        o4[(size_t)node * 32 + c4] = r;
        if (write_hbf)
            b2[(size_t)node * 32 + c4] = make_uint2(pack_bf2(r.x, r.y), pack_bf2(r.z, r.w));
    }
}

// ---------------- graph boundaries (batch is sorted) ----------------
__global__ void bounds_kernel(const int* __restrict__ batch, int* __restrict__ gs) {
    int n = blockIdx.x * 256 + threadIdx.x;
    if (n >= N_NODES) return;
    int bcur = batch[n];
    int prev = (n == 0) ? -1 : batch[n - 1];
    for (int g = prev + 1; g <= bcur; g++) gs[g] = n;
    if (n == N_NODES - 1) {
        for (int g = bcur + 1; g <= N_GRAPHS; g++) gs[g] = N_NODES;
    }
}

// ---------------- sum pool: orig-node order (batch sorted), h rows via inv ----------------
__global__ __launch_bounds__(256) void pool_kernel(const float* __restrict__ h,
                                                   const int* __restrict__ inv,
                                                   const int* __restrict__ batch,
                                                   float* __restrict__ sums) {
    int wave = threadIdx.x >> 6, l = threadIdx.x & 63;
    int nbase = (blockIdx.x * 4 + wave) * 8;
    const float2* h2 = (const float2*)h;
    float a0 = 0.f, a1 = 0.f;
    int g = -1;
#pragma unroll
    for (int i = 0; i < 8; i++) {
        int n = nbase + i;
        if (n >= N_NODES) break;
        int bg = batch[n];
        if (bg != g) {
            if (g >= 0) {
                atomicAdd(&sums[g * 128 + 2 * l], a0);
                atomicAdd(&sums[g * 128 + 2 * l + 1], a1);
            }
            g = bg; a0 = 0.f; a1 = 0.f;
        }
        int p = inv[n];  // wave-uniform
        float2 hv = h2[(size_t)p * 64 + l];
        a0 += hv.x; a1 += hv.y;
    }
    if (g >= 0) {
        atomicAdd(&sums[g * 128 + 2 * l], a0);
        atomicAdd(&sums[g * 128 + 2 * l + 1], a1);
    }
}

// ---------------- MLP head (divides pooled sums by count inline) ----------------
__global__ __launch_bounds__(512) void mlp_kernel(const float* __restrict__ sums,
                                                  const int* __restrict__ gs,
                                                  const float* __restrict__ Wh1,
                                                  const float* __restrict__ bh1,
                                                  const float* __restrict__ Wh2,
                                                  const float* __restrict__ bh2,
                                                  float* __restrict__ out) {
    int g = blockIdx.x;
    __shared__ float pl[128];
    __shared__ float red[8];
    int tid = threadIdx.x;
    if (tid < 128) {
        float cnt = fmaxf((float)(gs[g + 1] - gs[g]), 1.0f);
        pl[tid] = sums[g * 128 + tid] / cnt;
    }
    __syncthreads();
    float s = bh1[tid];
#pragma unroll 16
    for (int k = 0; k < 128; k++) s = fmaf(pl[k], Wh1[k * 512 + tid], s);
    float gl = 0.5f * s * (1.0f + erff(s * 0.70710678118654752f));
    float p = gl * Wh2[tid];
    for (int off = 32; off >= 1; off >>= 1) p += __shfl_down(p, off);
    if ((tid & 63) == 0) red[tid >> 6] = p;
    __syncthreads();
    if (tid == 0) {
        float tot = 0.f;
        for (int i = 0; i < 8; i++) tot += red[i];
        out[g] = tot + bh2[0];
    }
}

extern "C" void kernel_launch(void* const* d_in, const int* in_sizes, int n_in,
                              void* d_out, int out_size, void* d_ws, size_t ws_size,
                              hipStream_t stream) {
    const float* x = (const float*)d_in[0];
    const int* ei = (const int*)d_in[1];
    const float* eattr = (const float*)d_in[2];
    const int* batch = (const int*)d_in[3];
    const float* Wv = (const float*)d_in[4];
    const float* We = (const float*)d_in[5];
    const float* convW = (const float*)d_in[6];
    const float* convB = (const float*)d_in[7];
    const float* Wh1 = (const float*)d_in[8];
    const float* bh1 = (const float*)d_in[9];
    const float* Wh2 = (const float*)d_in[10];
    const float* bh2 = (const float*)d_in[11];
    float* out = (float*)d_out;

    const int* src = ei;
    const int* dst = ei + N_EDGES;

    // workspace carve-up (256B aligned) — total ~107 MB
    char* w = (char*)d_ws;
    size_t off = 0;
    auto alloc = [&](size_t bytes) -> char* {
        char* p = w + off;
        off += (bytes + 255) & ~(size_t)255;
        return p;
    };
    float* bufA = (float*)alloc((size_t)N_NODES * DCH * 4);               // h (ping)
    float* bufB = (float*)alloc((size_t)N_NODES * DCH * 4);               // h (pong)
    unsigned int* hbfA = (unsigned int*)alloc((size_t)N_NODES * 64 * 4);  // bf16 shadow ping
    unsigned int* hbfB = (unsigned int*)alloc((size_t)N_NODES * 64 * 4);  // bf16 shadow pong
    uint4* wb = (uint4*)alloc((size_t)N_LAYERS * 32 * 64 * 16);           // MFMA W frags
    int* deg = (int*)alloc((size_t)(N_NODES + 1) * 4);
    int* rowp = (int*)alloc((size_t)(N_NODES + 1) * 4);
    int* cursor = (int*)alloc((size_t)(N_NODES + 1) * 4);
    int* csum = (int*)alloc((size_t)NCHUNK * 4);
    int* coff = (int*)alloc((size_t)NCHUNK * 4);
    int* bhist = (int*)alloc((size_t)NCHUNK * 64 * 4);
    int* boff = (int*)alloc((size_t)NCHUNK * 64 * 4);
    int* nperm = (int*)alloc((size_t)N_NODES * 4);
    int* inv = (int*)alloc((size_t)N_NODES * 4);
    int* dstinv = (int*)alloc((size_t)N_EDGES * 4);
    uint4* erec = (uint4*)alloc((size_t)N_EDGES * 16);
    int* gs = (int*)alloc((size_t)(N_GRAPHS + 1) * 4);
    float* sums = (float*)alloc((size_t)N_GRAPHS * DCH * 4);
    (void)ws_size; (void)n_in; (void)in_sizes; (void)out_size;

    hipMemsetAsync(deg, 0, (size_t)(N_NODES + 1) * 4, stream);
    hipMemsetAsync(sums, 0, (size_t)N_GRAPHS * DCH * 4, stream);

    hist_kernel<<<N_EDGES / 256, 256, 0, stream>>>(dst, deg);
    dsort_hist_kernel<<<NCHUNK, 256, 0, stream>>>(deg, bhist);
    dsort_scan_kernel<<<1, 64, 0, stream>>>(bhist, boff);
    dsort_scatter_kernel<<<NCHUNK, 256, 0, stream>>>(deg, boff, nperm, inv);
    dstinv_kernel<<<N_EDGES / 256, 256, 0, stream>>>(dst, inv, dstinv);
    chunksum_kernel<<<NCHUNK, 256, 0, stream>>>(deg, nperm, csum);
    chunkscan_kernel<<<1, 256, 0, stream>>>(csum, coff);
    applyscan_kernel<<<NCHUNK, 256, 0, stream>>>(deg, nperm, coff, rowp, cursor);
    scatter_kernel<<<782 * 8, 256, 0, stream>>>(src, dstinv, inv, eattr, cursor, erec);
    sortrec_kernel<<<N_NODES / 4, 256, 0, stream>>>(rowp, erec);
    wconv_kernel<<<72, 256, 0, stream>>>(convW, wb);
    h0_kernel<<<N_NODES * 64 / 256, 256, 0, stream>>>(x, Wv, inv, bufA, hbfA);
    bounds_kernel<<<(N_NODES + 255) / 256, 256, 0, stream>>>(batch, gs);

    float* hcur = bufA;
    float* hnext = bufB;
    unsigned int* bfcur = hbfA;
    unsigned int* bfnext = hbfB;
    for (int layer = 0; layer < N_LAYERS; layer++) {
        layer_kernel<<<N_NODES / 16, 256, 0, stream>>>(
            hcur, bfcur, erec, rowp, We,
            (const short8*)(wb + (size_t)layer * 2048), convB + (size_t)layer * DCH,
            hnext, bfnext, (layer < N_LAYERS - 1) ? 1 : 0);
        float* t = hcur; hcur = hnext; hnext = t;
        unsigned int* tb = bfcur; bfcur = bfnext; bfnext = tb;
    }

    pool_kernel<<<(N_NODES + 31) / 32, 256, 0, stream>>>(hcur, inv, batch, sums);
    mlp_kernel<<<N_GRAPHS, 512, 0, stream>>>(sums, gs, Wh1, bh1, Wh2, bh2, out);
}

// Round 14
// 696.780 us; speedup vs baseline: 1.0976x; 1.0976x over previous
//
#include <hip/hip_runtime.h>
#include <math.h>

#define N_NODES 50000
#define N_EDGES 800000
#define DCH 128
#define N_LAYERS 9
#define N_GRAPHS 256
#define EPSF 1e-5f
#define NCHUNK 196   // ceil(50000/256)
#define NSLICE 4
#define SL_SZ 12500  // N_NODES / 4 slices (3.2 MB erec region per slice)

typedef __attribute__((ext_vector_type(8))) short short8;   // 8 bf16 = 4 VGPRs
typedef __attribute__((ext_vector_type(4))) float floatx4;

static __device__ __forceinline__ unsigned short f2bf(float f) {
    unsigned int u = __float_as_uint(f);
    unsigned int r = (u + 0x7fffu + ((u >> 16) & 1u)) >> 16;  // RNE
    return (unsigned short)r;
}
static __device__ __forceinline__ unsigned int pack_bf2(float a, float b) {
    return (unsigned int)f2bf(a) | ((unsigned int)f2bf(b) << 16);
}
static __device__ __forceinline__ float bflo(unsigned int u) { return __uint_as_float(u << 16); }
static __device__ __forceinline__ float bfhi(unsigned int u) { return __uint_as_float(u & 0xffff0000u); }

// descending-degree bucket (heavy nodes get low p -> dispatched first, LPT)
static __device__ __forceinline__ int dbucket(int d) { return 63 - min(d, 63); }

// ---------------- degree histogram (original node space) ----------------
__global__ void hist_kernel(const int* __restrict__ dst, int* __restrict__ deg) {
    int t = blockIdx.x * 256 + threadIdx.x;   // grid covers exactly N_EDGES
    atomicAdd(&deg[dst[t]], 1);
}

// ---------------- descending counting sort, two-level (no global hotspots) ----------------
__global__ __launch_bounds__(256) void dsort_hist_kernel(const int* __restrict__ deg,
                                                         int* __restrict__ bhist) {
    __shared__ int lh[64];
    int t = threadIdx.x;
    if (t < 64) lh[t] = 0;
    __syncthreads();
    int n = blockIdx.x * 256 + t;
    if (n < N_NODES) atomicAdd(&lh[dbucket(deg[n])], 1);
    __syncthreads();
    if (t < 64) bhist[blockIdx.x * 64 + t] = lh[t];
}

__global__ __launch_bounds__(64) void dsort_scan_kernel(const int* __restrict__ bhist,
                                                        int* __restrict__ boff) {
    __shared__ int tot[64];
    __shared__ int base[64];
    int b = threadIdx.x;  // thread b owns bucket b
    int s = 0;
    for (int blk = 0; blk < NCHUNK; blk++) s += bhist[blk * 64 + b];
    tot[b] = s;
    __syncthreads();
    if (b == 0) {
        int run = 0;
        for (int i = 0; i < 64; i++) { base[i] = run; run += tot[i]; }
    }
    __syncthreads();
    int run = base[b];
    for (int blk = 0; blk < NCHUNK; blk++) {
        boff[blk * 64 + b] = run;
        run += bhist[blk * 64 + b];
    }
}

__global__ __launch_bounds__(256) void dsort_scatter_kernel(const int* __restrict__ deg,
                                                            const int* __restrict__ boff,
                                                            int* __restrict__ nperm,
                                                            int* __restrict__ inv) {
    __shared__ int cur[64];
    int t = threadIdx.x;
    if (t < 64) cur[t] = boff[blockIdx.x * 64 + t];
    __syncthreads();
    int n = blockIdx.x * 256 + t;
    if (n < N_NODES) {
        int p = atomicAdd(&cur[dbucket(deg[n])], 1);  // LDS atomic, intra-block only
        nperm[p] = n;
        inv[n] = p;
    }
}

// dstinv[e] = inv[dst[e]] (one pass; avoids random inv gathers in scatter)
__global__ void dstinv_kernel(const int* __restrict__ dst, const int* __restrict__ inv,
                              int* __restrict__ dstinv) {
    int t = blockIdx.x * 256 + threadIdx.x;
    dstinv[t] = inv[dst[t]];
}

// ---------------- CSR build in p-space ----------------
__global__ __launch_bounds__(256) void chunksum_kernel(const int* __restrict__ deg,
                                                       const int* __restrict__ nperm,
                                                       int* __restrict__ csum) {
    int t = threadIdx.x;
    int i = blockIdx.x * 256 + t;
    int v = (i < N_NODES) ? deg[nperm[i]] : 0;
    __shared__ int sh[4];
    for (int off = 32; off >= 1; off >>= 1) v += __shfl_down(v, off);
    if ((t & 63) == 0) sh[t >> 6] = v;
    __syncthreads();
    if (t == 0) csum[blockIdx.x] = sh[0] + sh[1] + sh[2] + sh[3];
}

__global__ __launch_bounds__(256) void chunkscan_kernel(const int* __restrict__ csum,
                                                        int* __restrict__ coff) {
    __shared__ int sh[256];
    int t = threadIdx.x;
    sh[t] = (t < NCHUNK) ? csum[t] : 0;
    __syncthreads();
    for (int off = 1; off < 256; off <<= 1) {
        int v = (t >= off) ? sh[t - off] : 0;
        __syncthreads();
        sh[t] += v;
        __syncthreads();
    }
    if (t < NCHUNK) coff[t] = t ? sh[t - 1] : 0;  // exclusive
}

__global__ __launch_bounds__(256) void applyscan_kernel(const int* __restrict__ deg,
                                                        const int* __restrict__ nperm,
                                                        const int* __restrict__ coff,
                                                        int* __restrict__ rowp,
                                                        int* __restrict__ cursor) {
    __shared__ int sh[256];
    int t = threadIdx.x;
    int i = blockIdx.x * 256 + t;
    int d = (i < N_NODES) ? deg[nperm[i]] : 0;
    sh[t] = d;
    __syncthreads();
    for (int off = 1; off < 256; off <<= 1) {
        int v = (t >= off) ? sh[t - off] : 0;
        __syncthreads();
        sh[t] += v;
        __syncthreads();
    }
    int excl = coff[blockIdx.x] + (t ? sh[t - 1] : 0);
    if (i < N_NODES) {
        rowp[i] = excl;
        cursor[i] = excl;
    }
    if (i == N_NODES - 1) rowp[N_NODES] = N_EDGES;
}

// Sliced scatter in p-space: block (chunk, s) keeps edges whose p-space dst is
// in slice s -> contiguous erec region stays L2-resident (write merge).
__global__ __launch_bounds__(256) void scatter_kernel(const int* __restrict__ src,
                                                      const int* __restrict__ dstinv,
                                                      const int* __restrict__ inv,
                                                      const float* __restrict__ eattr,
                                                      int* __restrict__ cursor,
                                                      uint4* __restrict__ erec) {
    int s = blockIdx.x & (NSLICE - 1);
    int chunk = blockIdx.x / NSLICE;
    int e0 = chunk * 1024 + threadIdx.x * 4;
    if (e0 >= N_EDGES) return;
    int4 d4 = *(const int4*)(dstinv + e0);
#pragma unroll
    for (int k = 0; k < 4; k++) {
        int e = e0 + k;
        int d = (k == 0) ? d4.x : (k == 1) ? d4.y : (k == 2) ? d4.z : d4.w;
        if (d / SL_SZ == s) {
            int p = atomicAdd(&cursor[d], 1);
            float4 a = ((const float4*)eattr)[e];
            erec[p] = make_uint4((unsigned int)inv[src[e]],
                                 pack_bf2(a.x, a.y), pack_bf2(a.z, a.w), 0u);
        }
    }
}

// ---------------- conv weights -> MFMA B-fragment layout, bf16 ----------------
__global__ __launch_bounds__(256) void wconv_kernel(const float* __restrict__ convW,
                                                    uint4* __restrict__ wb) {
    int tid = blockIdx.x * 256 + threadIdx.x;  // 72 blocks * 256 = 18432 exactly
    int lane = tid & 63;
    int t = (tid >> 6) & 31;
    int layer = tid >> 11;
    int jt = t >> 2, kt = t & 3;
    int quad = lane >> 4, col = lane & 15;
    const float* Wl = convW + (size_t)layer * DCH * DCH;
    int kbase = kt * 32 + quad * 8;
    int ch = jt * 16 + col;
    unsigned int d0 = pack_bf2(Wl[(kbase + 0) * DCH + ch], Wl[(kbase + 1) * DCH + ch]);
    unsigned int d1 = pack_bf2(Wl[(kbase + 2) * DCH + ch], Wl[(kbase + 3) * DCH + ch]);
    unsigned int d2 = pack_bf2(Wl[(kbase + 4) * DCH + ch], Wl[(kbase + 5) * DCH + ch]);
    unsigned int d3 = pack_bf2(Wl[(kbase + 6) * DCH + ch], Wl[(kbase + 7) * DCH + ch]);
    wb[tid] = make_uint4(d0, d1, d2, d3);
}

// ---------------- h0 = x @ Wv, written to p-space rows ----------------
__global__ void h0_kernel(const float* __restrict__ x, const float* __restrict__ Wv,
                          const int* __restrict__ inv,
                          float* __restrict__ h, unsigned int* __restrict__ hbf) {
    int t = blockIdx.x * 256 + threadIdx.x;
    int n = t >> 6, l = t & 63;
    const float* xr = x + n * 13;
    float s0 = 0.f, s1 = 0.f;
#pragma unroll
    for (int j = 0; j < 13; j++) {
        float xv = xr[j];
        s0 = fmaf(xv, Wv[j * 128 + 2 * l], s0);
        s1 = fmaf(xv, Wv[j * 128 + 2 * l + 1], s1);
    }
    int p = inv[n];  // wave-uniform
    ((float2*)h)[(size_t)p * 64 + l] = make_float2(s0, s1);
    hbf[(size_t)p * 64 + l] = pack_bf2(s0, s1);
}

// ---------------- fused layer (p-space): aggregation + MFMA GEMM + epilogue ----------------
// Descending degree-sorted p-space: waves balanced at the barrier, heavy blocks
// first (LPT). hn carried through LDS (hsh) so the epilogue never re-reads hin.
#define VSTRIDE 68  // node row stride in uints (64 + 4 pad)
#define OLP 132     // epilogue row: 128 + 4
__global__ __launch_bounds__(256) void layer_kernel(const float* __restrict__ hin,
                                                    const unsigned int* __restrict__ hbfA,
                                                    const uint4* __restrict__ erec,
                                                    const int* __restrict__ rowp,
                                                    const float* __restrict__ We,
                                                    const short8* __restrict__ wbL,
                                                    const float* __restrict__ b,
                                                    float* __restrict__ hout,
                                                    unsigned int* __restrict__ hbfB,
                                                    int write_hbf) {
    __shared__ unsigned int vsh[16 * VSTRIDE];  // 4.25 KiB
    __shared__ float ol[16 * OLP];              // 8.25 KiB
    __shared__ float2 hsh[16 * 64];             // 8 KiB  (fp32 hn carry)
    int tid = threadIdx.x;
    int lane = tid & 63;
    int wave = tid >> 6;
    int nb = blockIdx.x * 16;  // 3125 blocks * 16 = 50000 exactly
    float w00 = We[0 * 128 + 2 * lane], w01 = We[0 * 128 + 2 * lane + 1];
    float w10 = We[1 * 128 + 2 * lane], w11 = We[1 * 128 + 2 * lane + 1];
    float w20 = We[2 * 128 + 2 * lane], w21 = We[2 * 128 + 2 * lane + 1];
    float w30 = We[3 * 128 + 2 * lane], w31 = We[3 * 128 + 2 * lane + 1];
    const float2* h2 = (const float2*)hin;
    // ---- aggregation: 4 nodes per wave, sequential ----
    for (int j = 0; j < 4; j++) {
        int nl = wave * 4 + j;
        int n = nb + nl;
        int start = rowp[n], end = rowp[n + 1];
        float a0 = 0.f, a1 = 0.f;
        int e = start;
        for (; e + 4 <= end; e += 4) {
            uint4 r0 = erec[e], r1 = erec[e + 1], r2 = erec[e + 2], r3 = erec[e + 3];
            unsigned int u0 = hbfA[(size_t)r0.x * 64 + lane];
            unsigned int u1 = hbfA[(size_t)r1.x * 64 + lane];
            unsigned int u2 = hbfA[(size_t)r2.x * 64 + lane];
            unsigned int u3 = hbfA[(size_t)r3.x * 64 + lane];
            float p0 = fmaf(bflo(r0.y), w00, fmaf(bfhi(r0.y), w10, fmaf(bflo(r0.z), w20, bfhi(r0.z) * w30)));
            float p1 = fmaf(bflo(r0.y), w01, fmaf(bfhi(r0.y), w11, fmaf(bflo(r0.z), w21, bfhi(r0.z) * w31)));
            float q0 = fmaf(bflo(r1.y), w00, fmaf(bfhi(r1.y), w10, fmaf(bflo(r1.z), w20, bfhi(r1.z) * w30)));
            float q1 = fmaf(bflo(r1.y), w01, fmaf(bfhi(r1.y), w11, fmaf(bflo(r1.z), w21, bfhi(r1.z) * w31)));
            float s0 = fmaf(bflo(r2.y), w00, fmaf(bfhi(r2.y), w10, fmaf(bflo(r2.z), w20, bfhi(r2.z) * w30)));
            float s1 = fmaf(bflo(r2.y), w01, fmaf(bfhi(r2.y), w11, fmaf(bflo(r2.z), w21, bfhi(r2.z) * w31)));
            float t0 = fmaf(bflo(r3.y), w00, fmaf(bfhi(r3.y), w10, fmaf(bflo(r3.z), w20, bfhi(r3.z) * w30)));
            float t1 = fmaf(bflo(r3.y), w01, fmaf(bfhi(r3.y), w11, fmaf(bflo(r3.z), w21, bfhi(r3.z) * w31)));
            a0 += fmaxf(bflo(u0) + p0, 0.f);
            a1 += fmaxf(bfhi(u0) + p1, 0.f);
            a0 += fmaxf(bflo(u1) + q0, 0.f);
            a1 += fmaxf(bfhi(u1) + q1, 0.f);
            a0 += fmaxf(bflo(u2) + s0, 0.f);
            a1 += fmaxf(bfhi(u2) + s1, 0.f);
            a0 += fmaxf(bflo(u3) + t0, 0.f);
            a1 += fmaxf(bfhi(u3) + t1, 0.f);
        }
        for (; e < end; e++) {
            uint4 r0 = erec[e];
            unsigned int u0 = hbfA[(size_t)r0.x * 64 + lane];
            float p0 = fmaf(bflo(r0.y), w00, fmaf(bfhi(r0.y), w10, fmaf(bflo(r0.z), w20, bfhi(r0.z) * w30)));
            float p1 = fmaf(bflo(r0.y), w01, fmaf(bfhi(r0.y), w11, fmaf(bflo(r0.z), w21, bfhi(r0.z) * w31)));
            a0 += fmaxf(bflo(u0) + p0, 0.f);
            a1 += fmaxf(bfhi(u0) + p1, 0.f);
        }
        float2 hn = h2[(size_t)n * 64 + lane];
        hsh[nl * 64 + lane] = hn;
        float vx = fmaf(hn.x, 1.f + EPSF, a0);
        float vy = fmaf(hn.y, 1.f + EPSF, a1);
        vsh[nl * VSTRIDE + lane] = pack_bf2(vx, vy);
    }
    __syncthreads();
    // ---- MFMA: shared 16-node A, each wave does jt = 2*wave, 2*wave+1 ----
    int col = lane & 15, quad = lane >> 4;
    short8 a[4];
#pragma unroll
    for (int kt = 0; kt < 4; kt++) {
        a[kt] = *(const short8*)(vsh + col * VSTRIDE + kt * 16 + quad * 4);
    }
#pragma unroll
    for (int jj = 0; jj < 2; jj++) {
        int jt = wave * 2 + jj;
        floatx4 acc = {0.f, 0.f, 0.f, 0.f};
#pragma unroll
        for (int kt = 0; kt < 4; kt++) {
            short8 bf = wbL[(jt * 4 + kt) * 64 + lane];
            acc = __builtin_amdgcn_mfma_f32_16x16x32_bf16(a[kt], bf, acc, 0, 0, 0);
        }
        float bv = b[jt * 16 + col];
#pragma unroll
        for (int r = 0; r < 4; r++) {
            ol[(quad * 4 + r) * OLP + jt * 16 + col] = fmaxf(acc[r] + bv, 0.f);
        }
    }
    __syncthreads();
    // ---- coalesced epilogue: 16 nodes x 32 float4-chunks = 512 items ----
    float4* o4 = (float4*)hout;
    uint2* b2 = (uint2*)hbfB;
#pragma unroll
    for (int i = 0; i < 2; i++) {
        int idx = i * 256 + tid;            // 0..511
        int nl = idx >> 5, c4 = idx & 31;
        int node = nb + nl;
        const float* row = ol + nl * OLP + c4 * 4;
        float2 h01 = hsh[nl * 64 + 2 * c4];
        float2 h23 = hsh[nl * 64 + 2 * c4 + 1];
        float4 r;
        r.x = row[0] + h01.x;
        r.y = row[1] + h01.y;
        r.z = row[2] + h23.x;
        r.w = row[3] + h23.y;
        o4[(size_t)node * 32 + c4] = r;
        if (write_hbf)
            b2[(size_t)node * 32 + c4] = make_uint2(pack_bf2(r.x, r.y), pack_bf2(r.z, r.w));
    }
}

// ---------------- graph boundaries (batch is sorted) ----------------
__global__ void bounds_kernel(const int* __restrict__ batch, int* __restrict__ gs) {
    int n = blockIdx.x * 256 + threadIdx.x;
    if (n >= N_NODES) return;
    int bcur = batch[n];
    int prev = (n == 0) ? -1 : batch[n - 1];
    for (int g = prev + 1; g <= bcur; g++) gs[g] = n;
    if (n == N_NODES - 1) {
        for (int g = bcur + 1; g <= N_GRAPHS; g++) gs[g] = N_NODES;
    }
}

// ---------------- sum pool: orig-node order (batch sorted), h rows via inv ----------------
__global__ __launch_bounds__(256) void pool_kernel(const float* __restrict__ h,
                                                   const int* __restrict__ inv,
                                                   const int* __restrict__ batch,
                                                   float* __restrict__ sums) {
    int wave = threadIdx.x >> 6, l = threadIdx.x & 63;
    int nbase = (blockIdx.x * 4 + wave) * 8;
    const float2* h2 = (const float2*)h;
    float a0 = 0.f, a1 = 0.f;
    int g = -1;
#pragma unroll
    for (int i = 0; i < 8; i++) {
        int n = nbase + i;
        if (n >= N_NODES) break;
        int bg = batch[n];
        if (bg != g) {
            if (g >= 0) {
                atomicAdd(&sums[g * 128 + 2 * l], a0);
                atomicAdd(&sums[g * 128 + 2 * l + 1], a1);
            }
            g = bg; a0 = 0.f; a1 = 0.f;
        }
        int p = inv[n];  // wave-uniform
        float2 hv = h2[(size_t)p * 64 + l];
        a0 += hv.x; a1 += hv.y;
    }
    if (g >= 0) {
        atomicAdd(&sums[g * 128 + 2 * l], a0);
        atomicAdd(&sums[g * 128 + 2 * l + 1], a1);
    }
}

// ---------------- MLP head (divides pooled sums by count inline) ----------------
__global__ __launch_bounds__(512) void mlp_kernel(const float* __restrict__ sums,
                                                  const int* __restrict__ gs,
                                                  const float* __restrict__ Wh1,
                                                  const float* __restrict__ bh1,
                                                  const float* __restrict__ Wh2,
                                                  const float* __restrict__ bh2,
                                                  float* __restrict__ out) {
    int g = blockIdx.x;
    __shared__ float pl[128];
    __shared__ float red[8];
    int tid = threadIdx.x;
    if (tid < 128) {
        float cnt = fmaxf((float)(gs[g + 1] - gs[g]), 1.0f);
        pl[tid] = sums[g * 128 + tid] / cnt;
    }
    __syncthreads();
    float s = bh1[tid];
#pragma unroll 16
    for (int k = 0; k < 128; k++) s = fmaf(pl[k], Wh1[k * 512 + tid], s);
    float gl = 0.5f * s * (1.0f + erff(s * 0.70710678118654752f));
    float p = gl * Wh2[tid];
    for (int off = 32; off >= 1; off >>= 1) p += __shfl_down(p, off);
    if ((tid & 63) == 0) red[tid >> 6] = p;
    __syncthreads();
    if (tid == 0) {
        float tot = 0.f;
        for (int i = 0; i < 8; i++) tot += red[i];
        out[g] = tot + bh2[0];
    }
}

extern "C" void kernel_launch(void* const* d_in, const int* in_sizes, int n_in,
                              void* d_out, int out_size, void* d_ws, size_t ws_size,
                              hipStream_t stream) {
    const float* x = (const float*)d_in[0];
    const int* ei = (const int*)d_in[1];
    const float* eattr = (const float*)d_in[2];
    const int* batch = (const int*)d_in[3];
    const float* Wv = (const float*)d_in[4];
    const float* We = (const float*)d_in[5];
    const float* convW = (const float*)d_in[6];
    const float* convB = (const float*)d_in[7];
    const float* Wh1 = (const float*)d_in[8];
    const float* bh1 = (const float*)d_in[9];
    const float* Wh2 = (const float*)d_in[10];
    const float* bh2 = (const float*)d_in[11];
    float* out = (float*)d_out;

    const int* src = ei;
    const int* dst = ei + N_EDGES;

    // workspace carve-up (256B aligned) — total ~107 MB
    char* w = (char*)d_ws;
    size_t off = 0;
    auto alloc = [&](size_t bytes) -> char* {
        char* p = w + off;
        off += (bytes + 255) & ~(size_t)255;
        return p;
    };
    float* bufA = (float*)alloc((size_t)N_NODES * DCH * 4);               // h (ping)
    float* bufB = (float*)alloc((size_t)N_NODES * DCH * 4);               // h (pong)
    unsigned int* hbfA = (unsigned int*)alloc((size_t)N_NODES * 64 * 4);  // bf16 shadow ping
    unsigned int* hbfB = (unsigned int*)alloc((size_t)N_NODES * 64 * 4);  // bf16 shadow pong
    uint4* wb = (uint4*)alloc((size_t)N_LAYERS * 32 * 64 * 16);           // MFMA W frags
    int* deg = (int*)alloc((size_t)(N_NODES + 1) * 4);
    int* rowp = (int*)alloc((size_t)(N_NODES + 1) * 4);
    int* cursor = (int*)alloc((size_t)(N_NODES + 1) * 4);
    int* csum = (int*)alloc((size_t)NCHUNK * 4);
    int* coff = (int*)alloc((size_t)NCHUNK * 4);
    int* bhist = (int*)alloc((size_t)NCHUNK * 64 * 4);
    int* boff = (int*)alloc((size_t)NCHUNK * 64 * 4);
    int* nperm = (int*)alloc((size_t)N_NODES * 4);
    int* inv = (int*)alloc((size_t)N_NODES * 4);
    int* dstinv = (int*)alloc((size_t)N_EDGES * 4);
    uint4* erec = (uint4*)alloc((size_t)N_EDGES * 16);
    int* gs = (int*)alloc((size_t)(N_GRAPHS + 1) * 4);
    float* sums = (float*)alloc((size_t)N_GRAPHS * DCH * 4);
    (void)ws_size; (void)n_in; (void)in_sizes; (void)out_size;

    hipMemsetAsync(deg, 0, (size_t)(N_NODES + 1) * 4, stream);
    hipMemsetAsync(sums, 0, (size_t)N_GRAPHS * DCH * 4, stream);

    hist_kernel<<<N_EDGES / 256, 256, 0, stream>>>(dst, deg);
    dsort_hist_kernel<<<NCHUNK, 256, 0, stream>>>(deg, bhist);
    dsort_scan_kernel<<<1, 64, 0, stream>>>(bhist, boff);
    dsort_scatter_kernel<<<NCHUNK, 256, 0, stream>>>(deg, boff, nperm, inv);
    dstinv_kernel<<<N_EDGES / 256, 256, 0, stream>>>(dst, inv, dstinv);
    chunksum_kernel<<<NCHUNK, 256, 0, stream>>>(deg, nperm, csum);
    chunkscan_kernel<<<1, 256, 0, stream>>>(csum, coff);
    applyscan_kernel<<<NCHUNK, 256, 0, stream>>>(deg, nperm, coff, rowp, cursor);
    scatter_kernel<<<782 * NSLICE, 256, 0, stream>>>(src, dstinv, inv, eattr, cursor, erec);
    wconv_kernel<<<72, 256, 0, stream>>>(convW, wb);
    h0_kernel<<<N_NODES * 64 / 256, 256, 0, stream>>>(x, Wv, inv, bufA, hbfA);
    bounds_kernel<<<(N_NODES + 255) / 256, 256, 0, stream>>>(batch, gs);

    float* hcur = bufA;
    float* hnext = bufB;
    unsigned int* bfcur = hbfA;
    unsigned int* bfnext = hbfB;
    for (int layer = 0; layer < N_LAYERS; layer++) {
        layer_kernel<<<N_NODES / 16, 256, 0, stream>>>(
            hcur, bfcur, erec, rowp, We,
            (const short8*)(wb + (size_t)layer * 2048), convB + (size_t)layer * DCH,
            hnext, bfnext, (layer < N_LAYERS - 1) ? 1 : 0);
        float* t = hcur; hcur = hnext; hnext = t;
        unsigned int* tb = bfcur; bfcur = bfnext; bfnext = tb;
    }

    pool_kernel<<<(N_NODES + 31) / 32, 256, 0, stream>>>(hcur, inv, batch, sums);
    mlp_kernel<<<N_GRAPHS, 512, 0, stream>>>(sums, gs, Wh1, bh1, Wh2, bh2, out);
}